// Round 3
// baseline (883.921 us; speedup 1.0000x reference)
//
#include <hip/hip_runtime.h>
#include <hip/hip_bf16.h>
#include <hip/hip_fp16.h>
#include <stdint.h>

#define DIM 256
#define NG 8192
#define KDIM 512      // 2*DIM (concat [readout | h])
#define GDIM 1024     // 4*DIM gates
#define N_ITERS 6
#define CHUNK 32

#define BM 128
#define BN 128
#define BK 64

typedef __hip_bfloat16 bf16;
typedef __attribute__((ext_vector_type(8))) short bf16x8;
typedef __attribute__((ext_vector_type(4))) float f32x4;
typedef __attribute__((ext_vector_type(8))) unsigned short u16x8;
typedef __attribute__((ext_vector_type(4))) unsigned short u16x4;

// ---------------- helpers --------------
__device__ __forceinline__ void async16(void* lds, const void* g) {
    __builtin_amdgcn_global_load_lds((const __attribute__((address_space(1))) void*)g,
                                     (__attribute__((address_space(3))) void*)lds, 16, 0, 0);
}
__device__ __forceinline__ float fast_sigmoid(float v) {
    return 1.0f / (1.0f + __expf(-v));
}
__device__ __forceinline__ float fast_tanh(float v) {
    float e = __expf(2.0f * v);
    return (e - 1.0f) / (e + 1.0f);
}
__device__ __forceinline__ unsigned short f2bf(float v) {
    __hip_bfloat16 t = __float2bfloat16(v);
    unsigned short u; __builtin_memcpy(&u, &t, 2); return u;
}
// fp16 <-> fp32 (x compression: 10 mantissa bits, 8x better than bf16)
__device__ __forceinline__ unsigned short f2h(float v) {
    __half t = __float2half_rn(v);
    unsigned short u; __builtin_memcpy(&u, &t, 2); return u;
}
__device__ __forceinline__ float h2f(unsigned short u) {
    __half t; __builtin_memcpy(&t, &u, 2);
    return __half2float(t);
}

// ---------------- CSR offsets from sorted batch ----------------
__global__ void k_offsets(const int* __restrict__ batch, int* __restrict__ offs, int n_nodes) {
    int v = blockIdx.x * blockDim.x + threadIdx.x;
    if (v >= n_nodes) return;
    int b = batch[v];
    int bp = (v == 0) ? -1 : batch[v - 1];
    for (int g = bp + 1; g <= b; ++g) offs[g] = v;
    if (v == n_nodes - 1) {
        for (int g = b + 1; g <= NG; ++g) offs[g] = n_nodes;
    }
}

// ---------------- W concat + gate-interleave + cast to bf16, bias sum ----------------
// Column layout: n = d*4 + gate (gate order i,f,g,o), so a 128-col GEMM tile holds
// all 4 gates for 32 consecutive d -> LSTM cell fused into the GEMM epilogue.
__global__ void k_prep_w(const float* __restrict__ Wih, const float* __restrict__ Whh,
                         const float* __restrict__ bih, const float* __restrict__ bhh,
                         bf16* __restrict__ Wcat, float* __restrict__ bsum) {
    int idx = blockIdx.x * blockDim.x + threadIdx.x;
    if (idx < GDIM * KDIM) {
        int n = idx >> 9;       // interleaved row of Wcat
        int k = idx & (KDIM - 1);
        int d = n >> 2, gate = n & 3;
        int j = gate * DIM + d; // original torch row
        float v = (k < DIM) ? Wih[j * DIM + k] : Whh[j * DIM + (k - DIM)];
        Wcat[idx] = __float2bfloat16(v);
    }
    if (idx < GDIM) {
        int d = idx >> 2, gate = idx & 3;
        int j = gate * DIM + d;
        bsum[idx] = bih[j] + bhh[j];
    }
}

// ---------------- zero-init h, c, and h-half of Acat0 ----------------
__global__ void k_zero(float* __restrict__ h, float* __restrict__ c, bf16* __restrict__ Acat0) {
    int i = blockIdx.x * blockDim.x + threadIdx.x;
    if (i >= NG * DIM) return;
    h[i] = 0.0f; c[i] = 0.0f;
    Acat0[(size_t)(i >> 8) * KDIM + DIM + (i & 255)] = __float2bfloat16(0.0f);
}

// ---------------- fused attention readout: one block per graph ----------------
// FIRST: reads fp32 x, writes fp16 copy xb (used by iters 2..6).
template <bool FIRST>
__global__ __launch_bounds__(256) void k_att(const float* __restrict__ xf,
                                             unsigned short* __restrict__ xb,
                                             const float* __restrict__ h,
                                             const int* __restrict__ offs,
                                             float* __restrict__ readout,
                                             bf16* __restrict__ AcatOut) {
    const int g = blockIdx.x;
    const int tid = threadIdx.x;
    const int wave = tid >> 6, lane = tid & 63;
    const int sub = lane >> 5, hl = lane & 31;   // half-wave: 32 lanes own one row

    __shared__ unsigned short xs[CHUNK][DIM];    // fp16 bits, 16 KB
    __shared__ float sc[CHUNK];
    __shared__ float esh[CHUNK];

    float hreg[8];
    {
        const float4 h0 = *(const float4*)&h[(size_t)g * DIM + hl * 8];
        const float4 h1 = *(const float4*)&h[(size_t)g * DIM + hl * 8 + 4];
        hreg[0] = h0.x; hreg[1] = h0.y; hreg[2] = h0.z; hreg[3] = h0.w;
        hreg[4] = h1.x; hreg[5] = h1.y; hreg[6] = h1.z; hreg[7] = h1.w;
    }

    const int start = offs[g], end = offs[g + 1];
    float racc = 0.0f;   // thread owns dim `tid`
    float m = 0.0f;      // running max, init 0 == the max(seg_max, 0) clamp
    float s = 0.0f;      // running sum of exp

    for (int base = start; base < end; base += CHUNK) {
        const int cnt = min(CHUNK, end - base);
        // Phase A: each wave stages 2 rows/iter (16B/lane); dot with h via half-wave reduce
        for (int i = wave * 2; i < cnt; i += 8) {
            const int r = i + sub;
            if (r < cnt) {
                u16x8 pk;
                float dt = 0.0f;
                if (FIRST) {
                    const float4 a = *(const float4*)&xf[(size_t)(base + r) * DIM + hl * 8];
                    const float4 b = *(const float4*)&xf[(size_t)(base + r) * DIM + hl * 8 + 4];
                    float xv[8] = {a.x, a.y, a.z, a.w, b.x, b.y, b.z, b.w};
                    #pragma unroll
                    for (int j = 0; j < 8; ++j) { pk[j] = f2h(xv[j]); dt = fmaf(xv[j], hreg[j], dt); }
                    *(u16x8*)&xb[(size_t)(base + r) * DIM + hl * 8] = pk;
                } else {
                    pk = *(const u16x8*)&xb[(size_t)(base + r) * DIM + hl * 8];
                    #pragma unroll
                    for (int j = 0; j < 8; ++j) dt = fmaf(h2f(pk[j]), hreg[j], dt);
                }
                *(u16x8*)&xs[r][hl * 8] = pk;
                #pragma unroll
                for (int off = 16; off > 0; off >>= 1) dt += __shfl_xor(dt, off);
                if (hl == 0) sc[r] = dt;
            }
        }
        __syncthreads();
        // Phase B: block-uniform online-softmax update
        float cmax = m;
        for (int i = 0; i < cnt; ++i) cmax = fmaxf(cmax, sc[i]);
        const float alpha = __expf(m - cmax);
        racc *= alpha;
        s *= alpha;
        if (tid < cnt) esh[tid] = __expf(sc[tid] - cmax);
        m = cmax;
        __syncthreads();
        // Phase C: weighted accumulation; thread tid owns dim tid
        for (int i = 0; i < cnt; ++i) {
            const float e = esh[i];
            s += e;
            racc = fmaf(e, h2f(xs[i][tid]), racc);
        }
        __syncthreads();
    }

    const float out = racc / (s + 1e-8f);
    readout[(size_t)g * DIM + tid] = out;
    AcatOut[(size_t)g * KDIM + tid] = __float2bfloat16(out);
}

// ---------------- GEMM + fused LSTM cell ----------------
// gates' = A(8192x512 bf16) @ Wcat(1024x512 bf16)^T + bsum, gate-interleaved cols.
// Epilogue: LDS transpose of each 32-row slice, compute c/h, write h into AcatNext.
__global__ __launch_bounds__(256) void k_gemm_cell(const bf16* __restrict__ A,
                                                   const bf16* __restrict__ W,
                                                   const float* __restrict__ bsum,
                                                   float* __restrict__ cst,
                                                   float* __restrict__ hst,
                                                   bf16* __restrict__ AcatN) {
    __shared__ union {
        struct { bf16 As[BM * BK]; bf16 Bs[BN * BK]; } st;  // 32 KB staging
        float ep[32][132];                                   // 16.9 KB epilogue transpose
    } sm;

    const int tid = threadIdx.x;
    const int wave = tid >> 6, lane = tid & 63;
    const int m0 = blockIdx.x * BM;
    const int n0 = blockIdx.y * BN;
    const int wr = wave >> 1, wc = wave & 1;

    f32x4 acc[4][4] = {};

    const int chunk = lane & 7;        // 16B chunk within a 128B row

    for (int k0 = 0; k0 < KDIM; k0 += BK) {
        #pragma unroll
        for (int i = 0; i < 4; ++i) {
            const int grp = wave * 32 + i * 8;
            async16(&sm.st.As[grp * BK],
                    A + (size_t)(m0 + grp + (lane >> 3)) * KDIM + k0 + chunk * 8);
        }
        #pragma unroll
        for (int i = 0; i < 4; ++i) {
            const int grp = wave * 32 + i * 8;
            async16(&sm.st.Bs[grp * BK],
                    W + (size_t)(n0 + grp + (lane >> 3)) * KDIM + k0 + chunk * 8);
        }
        asm volatile("s_waitcnt vmcnt(0)" ::: "memory");
        __syncthreads();

        #pragma unroll
        for (int ks = 0; ks < BK; ks += 32) {
            bf16x8 a[4], b[4];
            #pragma unroll
            for (int mi = 0; mi < 4; ++mi)
                a[mi] = *(const bf16x8*)&sm.st.As[(wr * 64 + mi * 16 + (lane & 15)) * BK + ks + (lane >> 4) * 8];
            #pragma unroll
            for (int ni = 0; ni < 4; ++ni)
                b[ni] = *(const bf16x8*)&sm.st.Bs[(wc * 64 + ni * 16 + (lane & 15)) * BK + ks + (lane >> 4) * 8];
            #pragma unroll
            for (int mi = 0; mi < 4; ++mi)
                #pragma unroll
                for (int ni = 0; ni < 4; ++ni)
                    acc[mi][ni] = __builtin_amdgcn_mfma_f32_16x16x32_bf16(a[mi], b[ni], acc[mi][ni], 0, 0, 0);
        }
        __syncthreads();
    }

    // ---- fused epilogue ----
    float bv[4];
    #pragma unroll
    for (int ni = 0; ni < 4; ++ni)
        bv[ni] = bsum[n0 + wc * 64 + ni * 16 + (lane & 15)];

    const int d0 = n0 >> 2;            // 32 d-values per block
    const int lr = tid >> 3;           // local row 0..31 in the 32-row slice
    const int dd = (tid & 7) * 4;      // 4 consecutive d per thread

    #pragma unroll
    for (int mi = 0; mi < 4; ++mi) {
        __syncthreads();
        // store this mi-slice (rows {mi*16..+15} U {64+mi*16..+15}) to LDS with bias
        #pragma unroll
        for (int ni = 0; ni < 4; ++ni) {
            const int colL = wc * 64 + ni * 16 + (lane & 15);
            #pragma unroll
            for (int r = 0; r < 4; ++r) {
                const int lrow = wr * 16 + (lane >> 4) * 4 + r;
                sm.ep[lrow][colL] = acc[mi][ni][r] + bv[ni];
            }
        }
        __syncthreads();
        // each thread: one row, 4 consecutive d -> full i,f,g,o quads
        const int grow = m0 + (lr >> 4) * 64 + mi * 16 + (lr & 15);
        const int d = d0 + dd;
        float co[4], cn[4], hn[4];
        *(float4*)co = *(const float4*)&cst[(size_t)grow * DIM + d];
        u16x4 hb;
        #pragma unroll
        for (int j = 0; j < 4; ++j) {
            const float4 q = *(const float4*)&sm.ep[lr][(dd + j) * 4]; // i,f,g,o
            cn[j] = fast_sigmoid(q.y) * co[j] + fast_sigmoid(q.x) * fast_tanh(q.z);
            hn[j] = fast_sigmoid(q.w) * fast_tanh(cn[j]);
            hb[j] = f2bf(hn[j]);
        }
        *(float4*)&cst[(size_t)grow * DIM + d] = *(float4*)cn;
        *(float4*)&hst[(size_t)grow * DIM + d] = *(float4*)hn;
        *(u16x4*)&AcatN[(size_t)grow * KDIM + DIM + d] = hb;
    }
}

// ---------------- final output: concat([h, readout]) ----------------
__global__ void k_out(const float* __restrict__ h, const float* __restrict__ readout,
                      float* __restrict__ out) {
    int idx = blockIdx.x * blockDim.x + threadIdx.x;
    if (idx >= NG * KDIM) return;
    const int g = idx >> 9, d = idx & (KDIM - 1);
    out[idx] = (d < DIM) ? h[(size_t)g * DIM + d] : readout[(size_t)g * DIM + (d - DIM)];
}

extern "C" void kernel_launch(void* const* d_in, const int* in_sizes, int n_in,
                              void* d_out, int out_size, void* d_ws, size_t ws_size,
                              hipStream_t stream) {
    const float* x     = (const float*)d_in[0];
    const int*   batch = (const int*)d_in[1];
    // d_in[2] = n_graphs scalar (8192, hardcoded)
    const float* Wih   = (const float*)d_in[3];
    const float* Whh   = (const float*)d_in[4];
    const float* bih   = (const float*)d_in[5];
    const float* bhh   = (const float*)d_in[6];
    const int n_nodes  = in_sizes[0] / DIM;
    float* out = (float*)d_out;

    char* ws = (char*)d_ws;
    size_t off = 0;
    auto alloc = [&](size_t bytes) -> void* {
        off = (off + 255) & ~(size_t)255;
        void* p = ws + off;
        off += bytes;
        return p;
    };
    int*   offs    = (int*)  alloc((size_t)(NG + 1) * sizeof(int));
    bf16*  Wcat    = (bf16*) alloc((size_t)GDIM * KDIM * sizeof(bf16));
    float* bsum    = (float*)alloc((size_t)GDIM * sizeof(float));
    bf16*  Acat0   = (bf16*) alloc((size_t)NG * KDIM * sizeof(bf16));
    bf16*  Acat1   = (bf16*) alloc((size_t)NG * KDIM * sizeof(bf16));
    float* h       = (float*)alloc((size_t)NG * DIM * sizeof(float));
    float* c       = (float*)alloc((size_t)NG * DIM * sizeof(float));
    float* readout = (float*)alloc((size_t)NG * DIM * sizeof(float));
    unsigned short* xb = (unsigned short*)alloc((size_t)n_nodes * DIM * sizeof(unsigned short));
    (void)ws_size; (void)n_in; (void)out_size;

    k_offsets<<<(n_nodes + 255) / 256, 256, 0, stream>>>(batch, offs, n_nodes);
    k_prep_w<<<(GDIM * KDIM + 255) / 256, 256, 0, stream>>>(Wih, Whh, bih, bhh, Wcat, bsum);
    k_zero<<<(NG * DIM + 255) / 256, 256, 0, stream>>>(h, c, Acat0);

    for (int it = 0; it < N_ITERS; ++it) {
        bf16* Ain  = (it & 1) ? Acat1 : Acat0;
        bf16* Aout = (it & 1) ? Acat0 : Acat1;   // epilogue writes h for NEXT iter (no race)
        if (it == 0)
            k_att<true><<<NG, 256, 0, stream>>>(x, xb, h, offs, readout, Ain);
        else
            k_att<false><<<NG, 256, 0, stream>>>(x, xb, h, offs, readout, Ain);
        k_gemm_cell<<<dim3(NG / BM, GDIM / BN), 256, 0, stream>>>(Ain, Wcat, bsum, c, h, Aout);
    }
    k_out<<<(NG * KDIM + 255) / 256, 256, 0, stream>>>(h, readout, out);
}

// Round 4
// 832.520 us; speedup vs baseline: 1.0617x; 1.0617x over previous
//
#include <hip/hip_runtime.h>
#include <hip/hip_bf16.h>
#include <hip/hip_fp16.h>
#include <stdint.h>

#define DIM 256
#define NG 8192
#define KDIM 512      // 2*DIM (concat [readout | h])
#define GDIM 1024     // 4*DIM gates
#define N_ITERS 6

#define BM 128
#define BN 128
#define BK 64

typedef __hip_bfloat16 bf16;
typedef __attribute__((ext_vector_type(8))) short bf16x8;
typedef __attribute__((ext_vector_type(4))) float f32x4;
typedef __attribute__((ext_vector_type(8))) unsigned short u16x8;
typedef __attribute__((ext_vector_type(4))) unsigned short u16x4;

// ---------------- helpers --------------
__device__ __forceinline__ void async16(void* lds, const void* g) {
    __builtin_amdgcn_global_load_lds((const __attribute__((address_space(1))) void*)g,
                                     (__attribute__((address_space(3))) void*)lds, 16, 0, 0);
}
__device__ __forceinline__ float fast_sigmoid(float v) {
    return 1.0f / (1.0f + __expf(-v));
}
__device__ __forceinline__ float fast_tanh(float v) {
    float e = __expf(2.0f * v);
    return (e - 1.0f) / (e + 1.0f);
}
__device__ __forceinline__ unsigned short f2bf(float v) {
    __hip_bfloat16 t = __float2bfloat16(v);
    unsigned short u; __builtin_memcpy(&u, &t, 2); return u;
}
__device__ __forceinline__ unsigned short f2h(float v) {
    __half t = __float2half_rn(v);
    unsigned short u; __builtin_memcpy(&u, &t, 2); return u;
}
__device__ __forceinline__ float h2f(unsigned short u) {
    __half t; __builtin_memcpy(&t, &u, 2);
    return __half2float(t);
}

// ---------------- fused prep: CSR offsets + W concat/interleave + zero-init ------------
// W column layout: n = d*4 + gate (i,f,g,o) so one 128-col GEMM tile holds all 4 gates
// for 32 consecutive d -> LSTM cell fuses into the GEMM epilogue.
__global__ void k_prep(const int* __restrict__ batch, int n_nodes, int* __restrict__ offs,
                       const float* __restrict__ Wih, const float* __restrict__ Whh,
                       const float* __restrict__ bih, const float* __restrict__ bhh,
                       bf16* __restrict__ Wcat, float* __restrict__ bsum,
                       float* __restrict__ h, float* __restrict__ c, bf16* __restrict__ Acat0) {
    const int idx = blockIdx.x * blockDim.x + threadIdx.x;
    if (idx < NG * DIM) {
        h[idx] = 0.0f; c[idx] = 0.0f;
        Acat0[(size_t)(idx >> 8) * KDIM + DIM + (idx & 255)] = __float2bfloat16(0.0f);
    }
    if (idx < GDIM * KDIM) {
        const int n = idx >> 9;
        const int k = idx & (KDIM - 1);
        const int d = n >> 2, gate = n & 3;
        const int j = gate * DIM + d;
        const float v = (k < DIM) ? Wih[j * DIM + k] : Whh[j * DIM + (k - DIM)];
        Wcat[idx] = __float2bfloat16(v);
    }
    if (idx < GDIM) {
        const int d = idx >> 2, gate = idx & 3;
        const int j = gate * DIM + d;
        bsum[idx] = bih[j] + bhh[j];
    }
    if (idx < n_nodes) {
        const int b = batch[idx];
        const int bp = (idx == 0) ? -1 : batch[idx - 1];
        for (int g = bp + 1; g <= b; ++g) offs[g] = idx;
        if (idx == n_nodes - 1)
            for (int g = b + 1; g <= NG; ++g) offs[g] = n_nodes;
    }
}

// ---------------- attention readout: ONE WAVE per graph, barrier-free, LDS-free --------
// Half-wave (32 lanes x 8 dims) per node row; online softmax entirely in registers;
// the loaded x row is reused for the weighted accumulate. Halves merged via shfl_xor(32).
// FIRST: reads fp32 x, writes fp16 copy xb. LAST: writes fp32 readout to out[:,256:512].
template <bool FIRST, bool LAST>
__global__ __launch_bounds__(256) void k_att(const float* __restrict__ xf,
                                             unsigned short* __restrict__ xb,
                                             const float* __restrict__ h,
                                             const int* __restrict__ offs,
                                             float* __restrict__ rout,   // LAST only: out + DIM
                                             bf16* __restrict__ AcatOut) {
    const int wave = threadIdx.x >> 6;
    const int g = (blockIdx.x << 2) + wave;
    const int lane = threadIdx.x & 63;
    const int half = lane >> 5, hl = lane & 31;

    float hreg[8];
    {
        const float4 a = *(const float4*)&h[(size_t)g * DIM + hl * 8];
        const float4 b = *(const float4*)&h[(size_t)g * DIM + hl * 8 + 4];
        hreg[0] = a.x; hreg[1] = a.y; hreg[2] = a.z; hreg[3] = a.w;
        hreg[4] = b.x; hreg[5] = b.y; hreg[6] = b.z; hreg[7] = b.w;
    }

    const int start = offs[g], end = offs[g + 1];
    float racc[8] = {0, 0, 0, 0, 0, 0, 0, 0};
    float m = 0.0f;   // running max; init 0 == the max(seg_max, 0) clamp
    float s = 0.0f;

    for (int r0 = start; r0 < end; r0 += 2) {
        const int r = r0 + half;
        const bool valid = (r < end);
        float xv[8];
        float dt = 0.0f;
        if (valid) {
            if (FIRST) {
                const float4 a = *(const float4*)&xf[(size_t)r * DIM + hl * 8];
                const float4 b = *(const float4*)&xf[(size_t)r * DIM + hl * 8 + 4];
                xv[0] = a.x; xv[1] = a.y; xv[2] = a.z; xv[3] = a.w;
                xv[4] = b.x; xv[5] = b.y; xv[6] = b.z; xv[7] = b.w;
                u16x8 pk;
                #pragma unroll
                for (int j = 0; j < 8; ++j) pk[j] = f2h(xv[j]);
                *(u16x8*)&xb[(size_t)r * DIM + hl * 8] = pk;
            } else {
                const u16x8 pk = *(const u16x8*)&xb[(size_t)r * DIM + hl * 8];
                #pragma unroll
                for (int j = 0; j < 8; ++j) xv[j] = h2f(pk[j]);
            }
            #pragma unroll
            for (int j = 0; j < 8; ++j) dt = fmaf(xv[j], hreg[j], dt);
        }
        #pragma unroll
        for (int off = 16; off > 0; off >>= 1) dt += __shfl_xor(dt, off);
        if (valid) {
            const float mn = fmaxf(m, dt);
            const float al = __expf(m - mn);
            const float e  = __expf(dt - mn);
            s = s * al + e;
            #pragma unroll
            for (int j = 0; j < 8; ++j) racc[j] = fmaf(racc[j], al, e * xv[j]);
            m = mn;
        }
    }

    // merge the two halves (online-softmax merge)
    const float mo = __shfl_xor(m, 32);
    const float M  = fmaxf(m, mo);
    const float al = __expf(m - M);
    s *= al;
    #pragma unroll
    for (int j = 0; j < 8; ++j) racc[j] *= al;
    s += __shfl_xor(s, 32);
    #pragma unroll
    for (int j = 0; j < 8; ++j) racc[j] += __shfl_xor(racc[j], 32);
    const float inv = 1.0f / (s + 1e-8f);
    float o[8];
    #pragma unroll
    for (int j = 0; j < 8; ++j) o[j] = racc[j] * inv;

    if (half == 0) {            // bf16 readout-half of A for the GEMM
        u16x8 pk;
        #pragma unroll
        for (int j = 0; j < 8; ++j) pk[j] = f2bf(o[j]);
        *(u16x8*)&AcatOut[(size_t)g * KDIM + hl * 8] = pk;
    } else if (LAST) {          // fp32 readout straight into out[:, 256:512]
        *(float4*)&rout[(size_t)g * KDIM + hl * 8]     = make_float4(o[0], o[1], o[2], o[3]);
        *(float4*)&rout[(size_t)g * KDIM + hl * 8 + 4] = make_float4(o[4], o[5], o[6], o[7]);
    }
}

// ---------------- GEMM + fused LSTM cell ----------------
// gates' = A(8192x512 bf16) @ Wcat(1024x512 bf16)^T + bsum, gate-interleaved cols.
// Epilogue: LDS transpose of each 32-row slice, compute c/h.
// LAST: write h straight into out[:,0:256] (stride KDIM); skip c/h/Acat stores.
template <bool LAST>
__global__ __launch_bounds__(256) void k_gemm_cell(const bf16* __restrict__ A,
                                                   const bf16* __restrict__ W,
                                                   const float* __restrict__ bsum,
                                                   float* __restrict__ cst,
                                                   float* __restrict__ hst,
                                                   bf16* __restrict__ AcatN,
                                                   float* __restrict__ hout) {
    __shared__ union {
        struct { bf16 As[BM * BK]; bf16 Bs[BN * BK]; } st;  // 32 KB staging
        float ep[32][132];                                   // epilogue transpose
    } sm;

    const int tid = threadIdx.x;
    const int wave = tid >> 6, lane = tid & 63;
    const int m0 = blockIdx.x * BM;
    const int n0 = blockIdx.y * BN;
    const int wr = wave >> 1, wc = wave & 1;

    f32x4 acc[4][4] = {};
    const int chunk = lane & 7;

    for (int k0 = 0; k0 < KDIM; k0 += BK) {
        #pragma unroll
        for (int i = 0; i < 4; ++i) {
            const int grp = wave * 32 + i * 8;
            async16(&sm.st.As[grp * BK],
                    A + (size_t)(m0 + grp + (lane >> 3)) * KDIM + k0 + chunk * 8);
        }
        #pragma unroll
        for (int i = 0; i < 4; ++i) {
            const int grp = wave * 32 + i * 8;
            async16(&sm.st.Bs[grp * BK],
                    W + (size_t)(n0 + grp + (lane >> 3)) * KDIM + k0 + chunk * 8);
        }
        asm volatile("s_waitcnt vmcnt(0)" ::: "memory");
        __syncthreads();

        #pragma unroll
        for (int ks = 0; ks < BK; ks += 32) {
            bf16x8 a[4], b[4];
            #pragma unroll
            for (int mi = 0; mi < 4; ++mi)
                a[mi] = *(const bf16x8*)&sm.st.As[(wr * 64 + mi * 16 + (lane & 15)) * BK + ks + (lane >> 4) * 8];
            #pragma unroll
            for (int ni = 0; ni < 4; ++ni)
                b[ni] = *(const bf16x8*)&sm.st.Bs[(wc * 64 + ni * 16 + (lane & 15)) * BK + ks + (lane >> 4) * 8];
            #pragma unroll
            for (int mi = 0; mi < 4; ++mi)
                #pragma unroll
                for (int ni = 0; ni < 4; ++ni)
                    acc[mi][ni] = __builtin_amdgcn_mfma_f32_16x16x32_bf16(a[mi], b[ni], acc[mi][ni], 0, 0, 0);
        }
        __syncthreads();
    }

    // ---- fused epilogue ----
    float bv[4];
    #pragma unroll
    for (int ni = 0; ni < 4; ++ni)
        bv[ni] = bsum[n0 + wc * 64 + ni * 16 + (lane & 15)];

    const int d0 = n0 >> 2;            // 32 d-values per block
    const int lr = tid >> 3;           // local row 0..31
    const int dd = (tid & 7) * 4;      // 4 consecutive d per thread

    #pragma unroll
    for (int mi = 0; mi < 4; ++mi) {
        __syncthreads();
        #pragma unroll
        for (int ni = 0; ni < 4; ++ni) {
            const int colL = wc * 64 + ni * 16 + (lane & 15);
            #pragma unroll
            for (int r = 0; r < 4; ++r) {
                const int lrow = wr * 16 + (lane >> 4) * 4 + r;
                sm.ep[lrow][colL] = acc[mi][ni][r] + bv[ni];
            }
        }
        __syncthreads();
        const int grow = m0 + (lr >> 4) * 64 + mi * 16 + (lr & 15);
        const int d = d0 + dd;
        float co[4], cn[4], hn[4];
        *(float4*)co = *(const float4*)&cst[(size_t)grow * DIM + d];
        u16x4 hb;
        #pragma unroll
        for (int j = 0; j < 4; ++j) {
            const float4 q = *(const float4*)&sm.ep[lr][(dd + j) * 4]; // i,f,g,o
            cn[j] = fast_sigmoid(q.y) * co[j] + fast_sigmoid(q.x) * fast_tanh(q.z);
            hn[j] = fast_sigmoid(q.w) * fast_tanh(cn[j]);
            hb[j] = f2bf(hn[j]);
        }
        if (LAST) {
            *(float4*)&hout[(size_t)grow * KDIM + d] = *(float4*)hn;   // out[:,0:256]
        } else {
            *(float4*)&cst[(size_t)grow * DIM + d] = *(float4*)cn;
            *(float4*)&hst[(size_t)grow * DIM + d] = *(float4*)hn;
            *(u16x4*)&AcatN[(size_t)grow * KDIM + DIM + d] = hb;
        }
    }
}

extern "C" void kernel_launch(void* const* d_in, const int* in_sizes, int n_in,
                              void* d_out, int out_size, void* d_ws, size_t ws_size,
                              hipStream_t stream) {
    const float* x     = (const float*)d_in[0];
    const int*   batch = (const int*)d_in[1];
    // d_in[2] = n_graphs scalar (8192, hardcoded)
    const float* Wih   = (const float*)d_in[3];
    const float* Whh   = (const float*)d_in[4];
    const float* bih   = (const float*)d_in[5];
    const float* bhh   = (const float*)d_in[6];
    const int n_nodes  = in_sizes[0] / DIM;
    float* out = (float*)d_out;

    char* ws = (char*)d_ws;
    size_t off = 0;
    auto alloc = [&](size_t bytes) -> void* {
        off = (off + 255) & ~(size_t)255;
        void* p = ws + off;
        off += bytes;
        return p;
    };
    int*   offs  = (int*)  alloc((size_t)(NG + 1) * sizeof(int));
    bf16*  Wcat  = (bf16*) alloc((size_t)GDIM * KDIM * sizeof(bf16));
    float* bsum  = (float*)alloc((size_t)GDIM * sizeof(float));
    bf16*  Acat0 = (bf16*) alloc((size_t)NG * KDIM * sizeof(bf16));
    bf16*  Acat1 = (bf16*) alloc((size_t)NG * KDIM * sizeof(bf16));
    float* h     = (float*)alloc((size_t)NG * DIM * sizeof(float));
    float* c     = (float*)alloc((size_t)NG * DIM * sizeof(float));
    unsigned short* xb = (unsigned short*)alloc((size_t)n_nodes * DIM * sizeof(unsigned short));
    (void)ws_size; (void)n_in; (void)out_size;

    k_prep<<<NG * DIM / 256, 256, 0, stream>>>(batch, n_nodes, offs, Wih, Whh, bih, bhh,
                                               Wcat, bsum, h, c, Acat0);

    for (int it = 0; it < N_ITERS; ++it) {
        bf16* Ain  = (it & 1) ? Acat1 : Acat0;
        bf16* Aout = (it & 1) ? Acat0 : Acat1;   // epilogue writes h for NEXT iter (no race)
        if (it == 0)
            k_att<true, false><<<NG / 4, 256, 0, stream>>>(x, xb, h, offs, nullptr, Ain);
        else if (it < N_ITERS - 1)
            k_att<false, false><<<NG / 4, 256, 0, stream>>>(x, xb, h, offs, nullptr, Ain);
        else
            k_att<false, true><<<NG / 4, 256, 0, stream>>>(x, xb, h, offs, out + DIM, Ain);

        if (it < N_ITERS - 1)
            k_gemm_cell<false><<<dim3(NG / BM, GDIM / BN), 256, 0, stream>>>(
                Ain, Wcat, bsum, c, h, Aout, nullptr);
        else
            k_gemm_cell<true><<<dim3(NG / BM, GDIM / BN), 256, 0, stream>>>(
                Ain, Wcat, bsum, c, nullptr, nullptr, out);
    }
}